// Round 11
// baseline (193.478 us; speedup 1.0000x reference)
//
#include <hip/hip_runtime.h>
#include <cmath>

#define NB 8
#define CC 256
#define NPIX 4096
#define QB 64
#define KVB 64
#define NT (NPIX / KVB)
#define LOG2E 1.4426950408889634f

typedef __attribute__((ext_vector_type(4))) float f32x4;
typedef __attribute__((ext_vector_type(8))) short s16x8;
typedef __attribute__((ext_vector_type(4))) unsigned short u16x4;
typedef __attribute__((ext_vector_type(4))) unsigned int u32x4;
typedef __attribute__((ext_vector_type(2))) unsigned int u32x2;

__device__ __forceinline__ unsigned short f2bf(float f) {
    union { float f; unsigned int u; } v; v.f = f;
    return (unsigned short)((v.u + 0x7FFFu + ((v.u >> 16) & 1u)) >> 16);
}

__device__ __forceinline__ unsigned int cvt_pk_bf16(float lo, float hi) {
    unsigned int r;
    asm("v_cvt_pk_bf16_f32 %0, %1, %2" : "=v"(r) : "v"(lo), "v"(hi));
    return r;  // low16 = bf16(lo), high16 = bf16(hi), RNE
}

__device__ __forceinline__ float u2f(unsigned int u) {
    union { unsigned int u; float f; } v; v.u = u; return v.f;
}

// ---------------------------------------------------------------------------
// proj_gemm: [Q(32);K(32);V(256)] = W · x  via MFMA, 2-term x hi/lo split.
// V now written M-TILED: Vt[b][n/64][c][n%64] so attention's PV A-frag loads
// are dense 128B rows (no 8KB-stride gather -> no L2 set conflicts).
// ---------------------------------------------------------------------------
__global__ __launch_bounds__(320) void proj_gemm_kernel(
    const float* __restrict__ x,
    const float* __restrict__ w1, const float* __restrict__ b1,
    const float* __restrict__ w2, const float* __restrict__ b2,
    const float* __restrict__ w3, const float* __restrict__ b3,
    unsigned short* __restrict__ Qm, unsigned short* __restrict__ Km,
    unsigned short* __restrict__ Vt)
{
    const int b  = blockIdx.x >> 6;
    const int n0 = (blockIdx.x & 63) * 64;
    const int wave = threadIdx.x >> 6;
    const int lane = threadIdx.x & 63;
    const int cl = lane & 15, g = lane >> 4;

    const float* arow[4];
#pragma unroll
    for (int ct = 0; ct < 4; ++ct) {
        const int row = wave * 64 + ct * 16 + cl;  // 0..319
        if (row < 32)       arow[ct] = w1 + (size_t)row * 256;
        else if (row < 64)  arow[ct] = w2 + (size_t)(row - 32) * 256;
        else                arow[ct] = w3 + (size_t)(row - 64) * 256;
    }

    const float* xb = x + (size_t)b * CC * NPIX + n0 + cl;

    f32x4 acc[4][4];
#pragma unroll
    for (int ct = 0; ct < 4; ++ct)
#pragma unroll
        for (int nt = 0; nt < 4; ++nt) acc[ct][nt] = (f32x4){0.f, 0.f, 0.f, 0.f};

    for (int ks = 0; ks < 8; ++ks) {
        const int c0 = ks * 32;
        s16x8 ah[4];
#pragma unroll
        for (int ct = 0; ct < 4; ++ct) {
            const float* ap = arow[ct] + c0 + g * 8;
            f32x4 a0 = *(const f32x4*)ap;
            f32x4 a1 = *(const f32x4*)(ap + 4);
            u32x4 u;
            u[0] = cvt_pk_bf16(a0[0], a0[1]); u[1] = cvt_pk_bf16(a0[2], a0[3]);
            u[2] = cvt_pk_bf16(a1[0], a1[1]); u[3] = cvt_pk_bf16(a1[2], a1[3]);
            ah[ct] = __builtin_bit_cast(s16x8, u);
        }
#pragma unroll
        for (int nt = 0; nt < 4; ++nt) {
            const float* xp = xb + (size_t)(c0 + g * 8) * NPIX + nt * 16;
            float xe[8];
#pragma unroll
            for (int e = 0; e < 8; ++e) xe[e] = xp[(size_t)e * NPIX];
            u32x4 uh, ul;
#pragma unroll
            for (int p = 0; p < 4; ++p) {
                const unsigned int hp = cvt_pk_bf16(xe[2 * p], xe[2 * p + 1]);
                const float h0 = u2f(hp << 16);
                const float h1 = u2f(hp & 0xffff0000u);
                uh[p] = hp;
                ul[p] = cvt_pk_bf16(xe[2 * p] - h0, xe[2 * p + 1] - h1);
            }
            const s16x8 bh = __builtin_bit_cast(s16x8, uh);
            const s16x8 bl = __builtin_bit_cast(s16x8, ul);
#pragma unroll
            for (int ct = 0; ct < 4; ++ct)
                acc[ct][nt] = __builtin_amdgcn_mfma_f32_16x16x32_bf16(ah[ct], bh, acc[ct][nt], 0, 0, 0);
#pragma unroll
            for (int ct = 0; ct < 4; ++ct)
                acc[ct][nt] = __builtin_amdgcn_mfma_f32_16x16x32_bf16(ah[ct], bl, acc[ct][nt], 0, 0, 0);
        }
    }

    if (wave == 0) {
#pragma unroll
        for (int ct = 0; ct < 4; ++ct) {
#pragma unroll
            for (int nt = 0; nt < 4; ++nt) {
                const int n = n0 + nt * 16 + cl;
                const int co = ct * 16 + g * 4;
                f32x4 v = acc[ct][nt];
                if (ct < 2) {  // Q, pre-scaled by log2e
                    const float q0 = (v[0] + b1[co + 0]) * LOG2E;
                    const float q1 = (v[1] + b1[co + 1]) * LOG2E;
                    const float q2 = (v[2] + b1[co + 2]) * LOG2E;
                    const float q3 = (v[3] + b1[co + 3]) * LOG2E;
                    u32x2 dd = {cvt_pk_bf16(q0, q1), cvt_pk_bf16(q2, q3)};
                    *(u32x2*)(Qm + ((size_t)b * NPIX + n) * 32 + co) = dd;
                } else {
                    const int ko = co - 32;
                    const float k0 = v[0] + b2[ko + 0];
                    const float k1 = v[1] + b2[ko + 1];
                    const float k2 = v[2] + b2[ko + 2];
                    const float k3 = v[3] + b2[ko + 3];
                    u32x2 dd = {cvt_pk_bf16(k0, k1), cvt_pk_bf16(k2, k3)};
                    *(u32x2*)(Km + ((size_t)b * NPIX + n) * 32 + ko) = dd;
                }
            }
        }
    } else {
        const int cvb = (wave - 1) * 64;
        const int mt0 = n0 >> 6;  // block's m-tile (n0 is 64-aligned)
#pragma unroll
        for (int ct = 0; ct < 4; ++ct) {
#pragma unroll
            for (int nt = 0; nt < 4; ++nt) {
                const int ni = nt * 16 + cl;  // 0..63 within tile
                const int cv = cvb + ct * 16 + g * 4;
#pragma unroll
                for (int r = 0; r < 4; ++r)
                    Vt[((size_t)(b * 64 + mt0) * CC + cv + r) * 64 + ni] =
                        f2bf(acc[ct][nt][r] + b3[cv + r]);
            }
        }
    }
}

// ---------------------------------------------------------------------------
// attn v10: R8's proven skeleton (8 waves, 512 grid, 2 barriers, asymmetric
// 16/48-channel PV ownership) with the V LDS round-trip DELETED: V read
// directly from the m-tiled Vt layout (dense 128B rows, L2-resident) at the
// TOP of each iter (T14 issue-early; owner softmax covers L2 latency).
// LDS traffic/block-iter 136KB -> 72KB; V-commit off the serial chain.
// Plus R10's no-shfl defer-max common path.
// ---------------------------------------------------------------------------
__global__ __launch_bounds__(512, 4) void attn_kernel(
    const unsigned short* __restrict__ Qm, const unsigned short* __restrict__ Km,
    const unsigned short* __restrict__ Vt, const float* __restrict__ gamma,
    float* __restrict__ out)
{
    __shared__ unsigned short Ps[QB * KVB];  // [q][m] 8KB, swizzled
    __shared__ float alpha_lds[QB];          // per-q rescale factor
    __shared__ float l_lds[QB];              // final denominators

    // XCD swizzle: each XCD gets one batch's 64 q-blocks (K+Vt fit its 4MB L2)
    const int bid = ((blockIdx.x & 7) << 6) + (blockIdx.x >> 3);
    const int b = bid >> 6;
    const int q0 = (bid & 63) * QB;

    const int t = threadIdx.x;
    const int wave = t >> 6;
    const int lane = t & 63;
    const int cl = lane & 15;
    const int g = lane >> 4;
    const bool owner = wave < 4;                     // softmax owner waves
    const int c0w = owner ? (wave * 16) : (64 + (wave - 4) * 48);
    const int NCT = owner ? 1 : 3;                   // PV channel sub-tiles
    const int qrow_own = (wave & 3) * 16 + cl;       // owned q-row (waves 0-3)

    // Q B-frag for the owned q-slice: B[k=d][col=q]
    const s16x8 qf = *(const s16x8*)(Qm + (((size_t)b * NPIX) + q0 + qrow_own) * 32 + g * 8);

    f32x4 acc[4][3];  // [qt][ct]: q = qt*16+cl, c = c0w + ct*16 + g*4 + r
#pragma unroll
    for (int qt = 0; qt < 4; ++qt)
#pragma unroll
        for (int ct = 0; ct < 3; ++ct)
            acc[qt][ct] = (f32x4){0.f, 0.f, 0.f, 0.f};

    float mrun = -__builtin_inff();
    float lrun = 0.f;  // per-lane partial; g-reduced once in epilogue

    const unsigned short* Kg = Km + (size_t)b * NPIX * 32;
    // per-lane V base: Vt[b][it][c0w+ct*16+cl][g*8], advance by CC*64 per iter
    const unsigned short* vbase = Vt + ((size_t)b * 64 * CC + c0w + cl) * 64 + g * 8;

    // prologue: K frags for tile 0 (owners)
    s16x8 kf[4];
    if (owner) {
#pragma unroll
        for (int mt = 0; mt < 4; ++mt)
            kf[mt] = *(const s16x8*)(Kg + (size_t)(mt * 16 + cl) * 32 + g * 8);
    }

    for (int it = 0; it < NT; ++it) {
        __syncthreads();  // barrier1: prev iter's Ps/alpha reads complete

        // V A-frags for THIS tile, direct from L2 (dense 128B rows).
        // Issued here; used after barrier2 (owner softmax covers latency).
        s16x8 av[2][3];
        {
            const unsigned short* vit = vbase + (size_t)it * CC * 64;
#pragma unroll
            for (int ch = 0; ch < 2; ++ch)
#pragma unroll
                for (int ct = 0; ct < 3; ++ct)
                    if (ct < NCT)
                        av[ch][ct] = *(const s16x8*)(vit + (size_t)(ct * 16) * 64 + ch * 32);
        }

        if (owner) {
            // QK^T for owned q-slice: S^T tiles D[row=m][col=q]
            f32x4 s[4];
            __builtin_amdgcn_s_setprio(1);
#pragma unroll
            for (int mt = 0; mt < 4; ++mt) {
                f32x4 z = (f32x4){0.f, 0.f, 0.f, 0.f};
                s[mt] = __builtin_amdgcn_mfma_f32_16x16x32_bf16(kf[mt], qf, z, 0, 0, 0);
            }
            __builtin_amdgcn_s_setprio(0);

            // per-lane local max only; no shfl in the common path (R10 micro)
            float ml = -__builtin_inff();
#pragma unroll
            for (int mt = 0; mt < 4; ++mt)
#pragma unroll
                for (int r = 0; r < 4; ++r) ml = fmaxf(ml, s[mt][r]);

            float alpha = 1.f;
            if (!__all(ml <= mrun + 8.f)) {  // defer-max violated (rare)
                ml = fmaxf(ml, __shfl_xor(ml, 16, 64));
                ml = fmaxf(ml, __shfl_xor(ml, 32, 64));  // row-uniform max
                const float mnew = fmaxf(mrun, ml);
                alpha = __builtin_amdgcn_exp2f(mrun - mnew);
                mrun = mnew;
                lrun *= alpha;
            }
            if (g == 0) alpha_lds[qrow_own] = alpha;

#pragma unroll
            for (int mt = 0; mt < 4; ++mt) {
#pragma unroll
                for (int r = 0; r < 4; ++r) {
                    s[mt][r] = __builtin_amdgcn_exp2f(s[mt][r] - mrun);
                    lrun += s[mt][r];  // per-lane partial (uniform mrun/alpha)
                }
            }

            // pack P slice -> Ps [q][m], swizzled (8B writes via cvt_pk)
#pragma unroll
            for (int mt = 0; mt < 4; ++mt) {
                u32x2 dd = {cvt_pk_bf16(s[mt][0], s[mt][1]),
                            cvt_pk_bf16(s[mt][2], s[mt][3])};
                *(u32x2*)(&Ps[qrow_own * 64 + ((mt * 16 + g * 4) ^ ((qrow_own & 7) << 3))]) = dd;
            }

            // prefetch next K frags (wrap; issued late to cap live VGPRs)
            const int mnext = ((it + 1) & (NT - 1)) * KVB;
#pragma unroll
            for (int mt = 0; mt < 4; ++mt)
                kf[mt] = *(const s16x8*)(Kg + (size_t)(mnext + mt * 16 + cl) * 32 + g * 8);
        }

        __syncthreads();  // barrier2: Ps + alpha visible

        // rescale acc by per-q alpha (rare thanks to defer-max)
        float aq[4];
#pragma unroll
        for (int qt = 0; qt < 4; ++qt) aq[qt] = alpha_lds[qt * 16 + cl];
        if (__any(aq[0] != 1.f || aq[1] != 1.f || aq[2] != 1.f || aq[3] != 1.f)) {
#pragma unroll
            for (int qt = 0; qt < 4; ++qt)
#pragma unroll
                for (int ct = 0; ct < 3; ++ct) acc[qt][ct] *= aq[qt];
        }

        // PV: acc[qt][ct] += mfma(A=V[c][m] (regs), B=P^T[m][q] (LDS))
#pragma unroll
        for (int ch = 0; ch < 2; ++ch) {
            s16x8 pb[4];
#pragma unroll
            for (int qt = 0; qt < 4; ++qt) {
                const int qr = qt * 16 + cl;
                pb[qt] = *(const s16x8*)(&Ps[qr * 64 + ((ch * 32 + g * 8) ^ ((qr & 7) << 3))]);
            }
            __builtin_amdgcn_s_setprio(1);
#pragma unroll
            for (int ct = 0; ct < 3; ++ct) {
                if (ct < NCT) {
#pragma unroll
                    for (int qt = 0; qt < 4; ++qt)
                        acc[qt][ct] = __builtin_amdgcn_mfma_f32_16x16x32_bf16(av[ch][ct], pb[qt], acc[qt][ct], 0, 0, 0);
                }
            }
            __builtin_amdgcn_s_setprio(0);
        }
    }

    // epilogue: owners reduce lrun over g-groups, share denominators
    if (owner) {
        lrun += __shfl_xor(lrun, 16, 64);
        lrun += __shfl_xor(lrun, 32, 64);
        if (g == 0) l_lds[qrow_own] = lrun;
    }
    __syncthreads();

    // coalesced [b][c][n] stores; second output = gamma*val
    const float gm = gamma[0];
    float* out2 = out + (size_t)NB * CC * NPIX;
#pragma unroll
    for (int qt = 0; qt < 4; ++qt) {
        const float inv = 1.f / l_lds[qt * 16 + cl];
        const int n = q0 + qt * 16 + cl;
#pragma unroll
        for (int ct = 0; ct < 3; ++ct) {
            if (ct < NCT) {
#pragma unroll
                for (int r = 0; r < 4; ++r) {
                    const int chn = c0w + ct * 16 + g * 4 + r;
                    const float val = acc[qt][ct][r] * inv;
                    const size_t idx = ((size_t)b * CC + chn) * NPIX + n;
                    out[idx] = val;
                    out2[idx] = gm * val;
                }
            }
        }
    }
}

// ---------------------------------------------------------------------------
extern "C" void kernel_launch(void* const* d_in, const int* in_sizes, int n_in,
                              void* d_out, int out_size, void* d_ws, size_t ws_size,
                              hipStream_t stream) {
    (void)in_sizes; (void)n_in; (void)out_size; (void)ws_size;
    const float* x     = (const float*)d_in[0];
    const float* w1    = (const float*)d_in[1];
    const float* b1    = (const float*)d_in[2];
    const float* w2    = (const float*)d_in[3];
    const float* b2    = (const float*)d_in[4];
    const float* w3    = (const float*)d_in[5];
    const float* b3    = (const float*)d_in[6];
    const float* gamma = (const float*)d_in[7];
    float* out = (float*)d_out;

    unsigned short* Qm = (unsigned short*)d_ws;                       // 2 MB
    unsigned short* Km = Qm + (size_t)NB * NPIX * 32;                 // 2 MB
    unsigned short* Vt = Km + (size_t)NB * NPIX * 32;                 // 16 MB (m-tiled)

    proj_gemm_kernel<<<NB * 64, 320, 0, stream>>>(x, w1, b1, w2, b2, w3, b3, Qm, Km, Vt);
    attn_kernel<<<NB * 64, 512, 0, stream>>>(Qm, Km, Vt, gamma, out);
}

// Round 12
// 135.743 us; speedup vs baseline: 1.4253x; 1.4253x over previous
//
#include <hip/hip_runtime.h>
#include <cmath>

#define NB 8
#define CC 256
#define NPIX 4096
#define QB 128
#define KVB 64
#define NT (NPIX / KVB)
#define LOG2E 1.4426950408889634f

typedef __attribute__((ext_vector_type(4))) float f32x4;
typedef __attribute__((ext_vector_type(16))) float f32x16;
typedef __attribute__((ext_vector_type(8))) short s16x8;
typedef __attribute__((ext_vector_type(4))) unsigned int u32x4;
typedef __attribute__((ext_vector_type(2))) unsigned int u32x2;

__device__ __forceinline__ unsigned short f2bf(float f) {
    union { float f; unsigned int u; } v; v.f = f;
    return (unsigned short)((v.u + 0x7FFFu + ((v.u >> 16) & 1u)) >> 16);
}

__device__ __forceinline__ unsigned int cvt_pk_bf16(float lo, float hi) {
    unsigned int r;
    asm("v_cvt_pk_bf16_f32 %0, %1, %2" : "=v"(r) : "v"(lo), "v"(hi));
    return r;  // low16 = bf16(lo), high16 = bf16(hi), RNE
}

__device__ __forceinline__ float u2f(unsigned int u) {
    union { unsigned int u; float f; } v; v.u = u; return v.f;
}

// ---------------------------------------------------------------------------
// proj_gemm: [Q(32);K(32);V(256)] = W · x  via MFMA, 2-term x hi/lo split.
// (R8 version — passed, ~14 µs; V layout [b][c][n])
// ---------------------------------------------------------------------------
__global__ __launch_bounds__(320) void proj_gemm_kernel(
    const float* __restrict__ x,
    const float* __restrict__ w1, const float* __restrict__ b1,
    const float* __restrict__ w2, const float* __restrict__ b2,
    const float* __restrict__ w3, const float* __restrict__ b3,
    unsigned short* __restrict__ Qm, unsigned short* __restrict__ Km,
    unsigned short* __restrict__ Vm)
{
    const int b  = blockIdx.x >> 6;
    const int n0 = (blockIdx.x & 63) * 64;
    const int wave = threadIdx.x >> 6;
    const int lane = threadIdx.x & 63;
    const int cl = lane & 15, g = lane >> 4;

    const float* arow[4];
#pragma unroll
    for (int ct = 0; ct < 4; ++ct) {
        const int row = wave * 64 + ct * 16 + cl;  // 0..319
        if (row < 32)       arow[ct] = w1 + (size_t)row * 256;
        else if (row < 64)  arow[ct] = w2 + (size_t)(row - 32) * 256;
        else                arow[ct] = w3 + (size_t)(row - 64) * 256;
    }

    const float* xb = x + (size_t)b * CC * NPIX + n0 + cl;

    f32x4 acc[4][4];
#pragma unroll
    for (int ct = 0; ct < 4; ++ct)
#pragma unroll
        for (int nt = 0; nt < 4; ++nt) acc[ct][nt] = (f32x4){0.f, 0.f, 0.f, 0.f};

    for (int ks = 0; ks < 8; ++ks) {
        const int c0 = ks * 32;
        s16x8 ah[4];
#pragma unroll
        for (int ct = 0; ct < 4; ++ct) {
            const float* ap = arow[ct] + c0 + g * 8;
            f32x4 a0 = *(const f32x4*)ap;
            f32x4 a1 = *(const f32x4*)(ap + 4);
            u32x4 u;
            u[0] = cvt_pk_bf16(a0[0], a0[1]); u[1] = cvt_pk_bf16(a0[2], a0[3]);
            u[2] = cvt_pk_bf16(a1[0], a1[1]); u[3] = cvt_pk_bf16(a1[2], a1[3]);
            ah[ct] = __builtin_bit_cast(s16x8, u);
        }
#pragma unroll
        for (int nt = 0; nt < 4; ++nt) {
            const float* xp = xb + (size_t)(c0 + g * 8) * NPIX + nt * 16;
            float xe[8];
#pragma unroll
            for (int e = 0; e < 8; ++e) xe[e] = xp[(size_t)e * NPIX];
            u32x4 uh, ul;
#pragma unroll
            for (int p = 0; p < 4; ++p) {
                const unsigned int hp = cvt_pk_bf16(xe[2 * p], xe[2 * p + 1]);
                const float h0 = u2f(hp << 16);
                const float h1 = u2f(hp & 0xffff0000u);
                uh[p] = hp;
                ul[p] = cvt_pk_bf16(xe[2 * p] - h0, xe[2 * p + 1] - h1);
            }
            const s16x8 bh = __builtin_bit_cast(s16x8, uh);
            const s16x8 bl = __builtin_bit_cast(s16x8, ul);
#pragma unroll
            for (int ct = 0; ct < 4; ++ct)
                acc[ct][nt] = __builtin_amdgcn_mfma_f32_16x16x32_bf16(ah[ct], bh, acc[ct][nt], 0, 0, 0);
#pragma unroll
            for (int ct = 0; ct < 4; ++ct)
                acc[ct][nt] = __builtin_amdgcn_mfma_f32_16x16x32_bf16(ah[ct], bl, acc[ct][nt], 0, 0, 0);
        }
    }

    if (wave == 0) {
#pragma unroll
        for (int ct = 0; ct < 4; ++ct) {
#pragma unroll
            for (int nt = 0; nt < 4; ++nt) {
                const int n = n0 + nt * 16 + cl;
                const int co = ct * 16 + g * 4;
                f32x4 v = acc[ct][nt];
                if (ct < 2) {  // Q, pre-scaled by log2e
                    const float q0 = (v[0] + b1[co + 0]) * LOG2E;
                    const float q1 = (v[1] + b1[co + 1]) * LOG2E;
                    const float q2 = (v[2] + b1[co + 2]) * LOG2E;
                    const float q3 = (v[3] + b1[co + 3]) * LOG2E;
                    u32x2 dd = {cvt_pk_bf16(q0, q1), cvt_pk_bf16(q2, q3)};
                    *(u32x2*)(Qm + ((size_t)b * NPIX + n) * 32 + co) = dd;
                } else {
                    const int ko = co - 32;
                    const float k0 = v[0] + b2[ko + 0];
                    const float k1 = v[1] + b2[ko + 1];
                    const float k2 = v[2] + b2[ko + 2];
                    const float k3 = v[3] + b2[ko + 3];
                    u32x2 dd = {cvt_pk_bf16(k0, k1), cvt_pk_bf16(k2, k3)};
                    *(u32x2*)(Km + ((size_t)b * NPIX + n) * 32 + ko) = dd;
                }
            }
        }
    } else {
        const int cvb = (wave - 1) * 64;
#pragma unroll
        for (int ct = 0; ct < 4; ++ct) {
#pragma unroll
            for (int nt = 0; nt < 4; ++nt) {
                const int n = n0 + nt * 16 + cl;
                const int cv = cvb + ct * 16 + g * 4;
#pragma unroll
                for (int r = 0; r < 4; ++r)
                    Vm[((size_t)b * CC + cv + r) * NPIX + n] = f2bf(acc[ct][nt][r] + b3[cv + r]);
            }
        }
    }
}

// ---------------------------------------------------------------------------
// attn v11: 32x32 MFMA + in-register P (T12). Each wave = independent flash
// attention for 32 q x 256 c: S^T = mfma32(K,Q) puts P lane-local; B-frags for
// PV built with cvt_pk + v_permlane32_swap (NO P LDS). LDS holds only V
// (double-buffered, global_load_lds with pre-swizzled source, ONE barrier/iter).
// grid 256 (8b x 32 q-blocks of 128), 256 thr / 4 waves, 2 blocks/CU.
// ---------------------------------------------------------------------------
__global__ __launch_bounds__(256, 2) void attn_kernel(
    const unsigned short* __restrict__ Qm, const unsigned short* __restrict__ Km,
    const unsigned short* __restrict__ Vm, const float* __restrict__ gamma,
    float* __restrict__ out)
{
    __shared__ unsigned short Vs[2][CC * KVB];  // 2 x 32KB, [c][m], XOR-chunked

    // XCD swizzle: each XCD gets one batch's 32 q-blocks (K+V fit its 4MB L2)
    const int bid = ((blockIdx.x & 7) << 5) + (blockIdx.x >> 3);
    const int b = bid >> 5;
    const int q0 = (bid & 31) * QB;

    const int t = threadIdx.x;
    const int wave = t >> 6;      // q-group 0..3
    const int lane = t & 63;
    const int q_ = lane & 31;     // q / c row within 32
    const int hi = lane >> 5;

    const int qrow = q0 + wave * 32 + q_;

    // Q B-frags (persistent): B[k=d][col=q], qf[kh] elem e: Q[qrow][16kh+8hi+e]
    s16x8 qf[2];
#pragma unroll
    for (int kh = 0; kh < 2; ++kh)
        qf[kh] = *(const s16x8*)(Qm + ((size_t)b * NPIX + qrow) * 32 + kh * 16 + hi * 8);

    f32x16 acc[8];
#pragma unroll
    for (int ct = 0; ct < 8; ++ct) acc[ct] = (f32x16){};

    float mrun = -__builtin_inff();
    float lrun = 0.f;  // per-lane partial over this lane's m's; +shfl(32) at end

    const unsigned short* Kg = Km + (size_t)b * NPIX * 32;
    const unsigned short* Vg = Vm + (size_t)b * CC * NPIX;

    // V staging (global_load_lds): linear LDS dest (16B/thread), source column
    // pre-swizzled: thread t covers rows vr0+32i, global chunk (t&7)^(vr0&7).
    const int vr0 = t >> 3;                    // 0..31
    const int cg = (t & 7) ^ (vr0 & 7);
    const unsigned short* vsrc = Vg + (size_t)vr0 * NPIX + cg * 8;

#define STAGE_V(tile, buf_)                                                    \
    {                                                                          \
        const int mm_ = (tile) * KVB;                                          \
        _Pragma("unroll")                                                      \
        for (int i_ = 0; i_ < 8; ++i_)                                         \
            __builtin_amdgcn_global_load_lds(                                  \
                (const __attribute__((address_space(1))) void*)(vsrc + (size_t)i_ * 32 * NPIX + mm_), \
                (__attribute__((address_space(3))) void*)(&Vs[buf_][i_ * 2048 + t * 8]), \
                16, 0, 0);                                                     \
    }

    // K A-frags: A[row=m][k=d], kf[mt][kh] elem e: K[m0+32mt+q_][16kh+8hi+e]
    s16x8 kf[2][2];
#define LOAD_KF(mm_)                                                           \
    {                                                                          \
        _Pragma("unroll")                                                      \
        for (int mt_ = 0; mt_ < 2; ++mt_)                                      \
            _Pragma("unroll")                                                  \
            for (int kh_ = 0; kh_ < 2; ++kh_)                                  \
                kf[mt_][kh_] = *(const s16x8*)(Kg + (size_t)((mm_) + 32 * mt_ + q_) * 32 + kh_ * 16 + hi * 8); \
    }

    // prologue: stage tile 0 into buf 0; K frags for tile 0
    STAGE_V(0, 0)
    LOAD_KF(0)

    int cur = 0;
    for (int it = 0; it < NT; ++it) {
        __syncthreads();  // drains tile-it staging (vmcnt) + prev reads done

        // issue next tile's staging into the other buffer (flies across compute)
        if (it < NT - 1) STAGE_V(it + 1, cur ^ 1)

        // QK^T: S^T[m][q] via mfma32, m = (reg&3)+8*(reg>>2)+4hi (+32 for s1)
        f32x16 z = (f32x16){};
        f32x16 s0 = __builtin_amdgcn_mfma_f32_32x32x16_bf16(kf[0][0], qf[0], z, 0, 0, 0);
        s0 = __builtin_amdgcn_mfma_f32_32x32x16_bf16(kf[0][1], qf[1], s0, 0, 0, 0);
        f32x16 s1 = __builtin_amdgcn_mfma_f32_32x32x16_bf16(kf[1][0], qf[0], z, 0, 0, 0);
        s1 = __builtin_amdgcn_mfma_f32_32x32x16_bf16(kf[1][1], qf[1], s1, 0, 0, 0);

        // prefetch K frags for next tile (wrap; kf dead after QK above)
        LOAD_KF((((it + 1) & (NT - 1))) * KVB)

        // online softmax (log2 domain; Q pre-scaled). Per-lane local max.
        float ml = -__builtin_inff();
#pragma unroll
        for (int r = 0; r < 16; ++r) ml = fmaxf(ml, s0[r]);
#pragma unroll
        for (int r = 0; r < 16; ++r) ml = fmaxf(ml, s1[r]);

        if (!__all(ml <= mrun + 8.f)) {  // defer-max violated (rare)
            ml = fmaxf(ml, __shfl_xor(ml, 32, 64));  // row max (pair lane)
            const float mnew = fmaxf(mrun, ml);
            const float alpha = __builtin_amdgcn_exp2f(mrun - mnew);
            mrun = mnew;
            lrun *= alpha;
#pragma unroll
            for (int ct = 0; ct < 8; ++ct) acc[ct] *= alpha;
        }

#pragma unroll
        for (int r = 0; r < 16; ++r) { s0[r] = __builtin_amdgcn_exp2f(s0[r] - mrun); lrun += s0[r]; }
#pragma unroll
        for (int r = 0; r < 16; ++r) { s1[r] = __builtin_amdgcn_exp2f(s1[r] - mrun); lrun += s1[r]; }

        // pack P words: w[mt][s][j]; w[.][s][0]=P[8s+4hi,+1], [1]=P[8s+4hi+2,+3]
        unsigned int w0[4][2], w1[4][2];
#pragma unroll
        for (int s = 0; s < 4; ++s) {
            w0[s][0] = cvt_pk_bf16(s0[4 * s + 0], s0[4 * s + 1]);
            w0[s][1] = cvt_pk_bf16(s0[4 * s + 2], s0[4 * s + 3]);
            w1[s][0] = cvt_pk_bf16(s1[4 * s + 0], s1[4 * s + 1]);
            w1[s][1] = cvt_pk_bf16(s1[4 * s + 2], s1[4 * s + 3]);
        }

        // PV per 16-m block t4: B-frag via 2 permlane32_swap; A from Vs[cur]
#pragma unroll
        for (int t4 = 0; t4 < 4; ++t4) {
            const int lt = t4 & 1;
            unsigned int a0 = (t4 < 2) ? w0[2 * lt][0] : w1[2 * lt][0];
            unsigned int b0 = (t4 < 2) ? w0[2 * lt + 1][0] : w1[2 * lt + 1][0];
            unsigned int a1 = (t4 < 2) ? w0[2 * lt][1] : w1[2 * lt][1];
            unsigned int b1 = (t4 < 2) ? w0[2 * lt + 1][1] : w1[2 * lt + 1][1];
            // D' = [D_lo|S_lo], S' = [D_hi|S_hi]
            asm("v_permlane32_swap_b32 %0, %1" : "+v"(a0), "+v"(b0));
            asm("v_permlane32_swap_b32 %0, %1" : "+v"(a1), "+v"(b1));
            u32x4 bw = {a0, a1, b0, b1};  // B words 0..3: P[16t4+8hi+2w..+1][q]
            const s16x8 pb = __builtin_bit_cast(s16x8, bw);

            __builtin_amdgcn_s_setprio(1);
#pragma unroll
            for (int ct = 0; ct < 8; ++ct) {
                const int c = 32 * ct + q_;
                const int slot = (2 * t4 + hi) ^ (c & 7);
                const s16x8 av = *(const s16x8*)(&Vs[cur][c * 64 + slot * 8]);
                acc[ct] = __builtin_amdgcn_mfma_f32_32x32x16_bf16(av, pb, acc[ct], 0, 0, 0);
            }
            __builtin_amdgcn_s_setprio(0);
        }

        cur ^= 1;
    }

    // epilogue: finish row sums (pair lane holds the other half of m's)
    lrun += __shfl_xor(lrun, 32, 64);
    const float inv = 1.f / lrun;
    const float gm = gamma[0];
    float* out2 = out + (size_t)NB * CC * NPIX;
    const int n = qrow;
#pragma unroll
    for (int ct = 0; ct < 8; ++ct) {
#pragma unroll
        for (int r = 0; r < 16; ++r) {
            const int c = 32 * ct + (r & 3) + 8 * (r >> 2) + 4 * hi;
            const float val = acc[ct][r] * inv;
            const size_t idx = ((size_t)b * CC + c) * NPIX + n;
            out[idx] = val;
            out2[idx] = gm * val;
        }
    }
}

// ---------------------------------------------------------------------------
extern "C" void kernel_launch(void* const* d_in, const int* in_sizes, int n_in,
                              void* d_out, int out_size, void* d_ws, size_t ws_size,
                              hipStream_t stream) {
    (void)in_sizes; (void)n_in; (void)out_size; (void)ws_size;
    const float* x     = (const float*)d_in[0];
    const float* w1    = (const float*)d_in[1];
    const float* b1    = (const float*)d_in[2];
    const float* w2    = (const float*)d_in[3];
    const float* b2    = (const float*)d_in[4];
    const float* w3    = (const float*)d_in[5];
    const float* b3    = (const float*)d_in[6];
    const float* gamma = (const float*)d_in[7];
    float* out = (float*)d_out;

    unsigned short* Qm = (unsigned short*)d_ws;                       // 2 MB
    unsigned short* Km = Qm + (size_t)NB * NPIX * 32;                 // 2 MB
    unsigned short* Vm = Km + (size_t)NB * NPIX * 32;                 // 16 MB

    proj_gemm_kernel<<<NB * 64, 320, 0, stream>>>(x, w1, b1, w2, b2, w3, b3, Qm, Km, Vm);
    attn_kernel<<<NB * 32, 256, 0, stream>>>(Qm, Km, Vm, gamma, out);
}

// Round 13
// 124.586 us; speedup vs baseline: 1.5530x; 1.0896x over previous
//
#include <hip/hip_runtime.h>
#include <cmath>

#define NB 8
#define CC 256
#define NPIX 4096
#define QB 128
#define KVB 64
#define NT2 32  // tiles per KV-half
#define LOG2E 1.4426950408889634f

typedef __attribute__((ext_vector_type(4))) float f32x4;
typedef __attribute__((ext_vector_type(16))) float f32x16;
typedef __attribute__((ext_vector_type(8))) short s16x8;
typedef __attribute__((ext_vector_type(4))) unsigned int u32x4;
typedef __attribute__((ext_vector_type(2))) unsigned int u32x2;

__device__ __forceinline__ unsigned short f2bf(float f) {
    union { float f; unsigned int u; } v; v.f = f;
    return (unsigned short)((v.u + 0x7FFFu + ((v.u >> 16) & 1u)) >> 16);
}

__device__ __forceinline__ unsigned int cvt_pk_bf16(float lo, float hi) {
    unsigned int r;
    asm("v_cvt_pk_bf16_f32 %0, %1, %2" : "=v"(r) : "v"(lo), "v"(hi));
    return r;  // low16 = bf16(lo), high16 = bf16(hi), RNE
}

__device__ __forceinline__ float u2f(unsigned int u) {
    union { unsigned int u; float f; } v; v.u = u; return v.f;
}

// ---------------------------------------------------------------------------
// proj_gemm: [Q(32);K(32);V(256)] = W · x  via MFMA, 2-term x hi/lo split.
// (unchanged — passed, ~14 µs; V layout [b][c][n])
// ---------------------------------------------------------------------------
__global__ __launch_bounds__(320) void proj_gemm_kernel(
    const float* __restrict__ x,
    const float* __restrict__ w1, const float* __restrict__ b1,
    const float* __restrict__ w2, const float* __restrict__ b2,
    const float* __restrict__ w3, const float* __restrict__ b3,
    unsigned short* __restrict__ Qm, unsigned short* __restrict__ Km,
    unsigned short* __restrict__ Vm)
{
    const int b  = blockIdx.x >> 6;
    const int n0 = (blockIdx.x & 63) * 64;
    const int wave = threadIdx.x >> 6;
    const int lane = threadIdx.x & 63;
    const int cl = lane & 15, g = lane >> 4;

    const float* arow[4];
#pragma unroll
    for (int ct = 0; ct < 4; ++ct) {
        const int row = wave * 64 + ct * 16 + cl;  // 0..319
        if (row < 32)       arow[ct] = w1 + (size_t)row * 256;
        else if (row < 64)  arow[ct] = w2 + (size_t)(row - 32) * 256;
        else                arow[ct] = w3 + (size_t)(row - 64) * 256;
    }

    const float* xb = x + (size_t)b * CC * NPIX + n0 + cl;

    f32x4 acc[4][4];
#pragma unroll
    for (int ct = 0; ct < 4; ++ct)
#pragma unroll
        for (int nt = 0; nt < 4; ++nt) acc[ct][nt] = (f32x4){0.f, 0.f, 0.f, 0.f};

    for (int ks = 0; ks < 8; ++ks) {
        const int c0 = ks * 32;
        s16x8 ah[4];
#pragma unroll
        for (int ct = 0; ct < 4; ++ct) {
            const float* ap = arow[ct] + c0 + g * 8;
            f32x4 a0 = *(const f32x4*)ap;
            f32x4 a1 = *(const f32x4*)(ap + 4);
            u32x4 u;
            u[0] = cvt_pk_bf16(a0[0], a0[1]); u[1] = cvt_pk_bf16(a0[2], a0[3]);
            u[2] = cvt_pk_bf16(a1[0], a1[1]); u[3] = cvt_pk_bf16(a1[2], a1[3]);
            ah[ct] = __builtin_bit_cast(s16x8, u);
        }
#pragma unroll
        for (int nt = 0; nt < 4; ++nt) {
            const float* xp = xb + (size_t)(c0 + g * 8) * NPIX + nt * 16;
            float xe[8];
#pragma unroll
            for (int e = 0; e < 8; ++e) xe[e] = xp[(size_t)e * NPIX];
            u32x4 uh, ul;
#pragma unroll
            for (int p = 0; p < 4; ++p) {
                const unsigned int hp = cvt_pk_bf16(xe[2 * p], xe[2 * p + 1]);
                const float h0 = u2f(hp << 16);
                const float h1 = u2f(hp & 0xffff0000u);
                uh[p] = hp;
                ul[p] = cvt_pk_bf16(xe[2 * p] - h0, xe[2 * p + 1] - h1);
            }
            const s16x8 bh = __builtin_bit_cast(s16x8, uh);
            const s16x8 bl = __builtin_bit_cast(s16x8, ul);
#pragma unroll
            for (int ct = 0; ct < 4; ++ct)
                acc[ct][nt] = __builtin_amdgcn_mfma_f32_16x16x32_bf16(ah[ct], bh, acc[ct][nt], 0, 0, 0);
#pragma unroll
            for (int ct = 0; ct < 4; ++ct)
                acc[ct][nt] = __builtin_amdgcn_mfma_f32_16x16x32_bf16(ah[ct], bl, acc[ct][nt], 0, 0, 0);
        }
    }

    if (wave == 0) {
#pragma unroll
        for (int ct = 0; ct < 4; ++ct) {
#pragma unroll
            for (int nt = 0; nt < 4; ++nt) {
                const int n = n0 + nt * 16 + cl;
                const int co = ct * 16 + g * 4;
                f32x4 v = acc[ct][nt];
                if (ct < 2) {  // Q, pre-scaled by log2e
                    const float q0 = (v[0] + b1[co + 0]) * LOG2E;
                    const float q1 = (v[1] + b1[co + 1]) * LOG2E;
                    const float q2 = (v[2] + b1[co + 2]) * LOG2E;
                    const float q3 = (v[3] + b1[co + 3]) * LOG2E;
                    u32x2 dd = {cvt_pk_bf16(q0, q1), cvt_pk_bf16(q2, q3)};
                    *(u32x2*)(Qm + ((size_t)b * NPIX + n) * 32 + co) = dd;
                } else {
                    const int ko = co - 32;
                    const float k0 = v[0] + b2[ko + 0];
                    const float k1 = v[1] + b2[ko + 1];
                    const float k2 = v[2] + b2[ko + 2];
                    const float k3 = v[3] + b2[ko + 3];
                    u32x2 dd = {cvt_pk_bf16(k0, k1), cvt_pk_bf16(k2, k3)};
                    *(u32x2*)(Km + ((size_t)b * NPIX + n) * 32 + ko) = dd;
                }
            }
        }
    } else {
        const int cvb = (wave - 1) * 64;
#pragma unroll
        for (int ct = 0; ct < 4; ++ct) {
#pragma unroll
            for (int nt = 0; nt < 4; ++nt) {
                const int n = n0 + nt * 16 + cl;
                const int cv = cvb + ct * 16 + g * 4;
#pragma unroll
                for (int r = 0; r < 4; ++r)
                    Vm[((size_t)b * CC + cv + r) * NPIX + n] = f2bf(acc[ct][nt][r] + b3[cv + r]);
            }
        }
    }
}

// ---------------------------------------------------------------------------
// attn v12: R12's in-register-P wave structure (32x32 MFMA, cvt_pk+permlane,
// global_load_lds V, 1 barrier/iter) + KV-SPLIT: 8 waves = 4 q-slices x 2
// kv-halves; each half double-buffers its own V (LDS 128KB). 8 waves/CU =
// 2/SIMD (was 1) -> waves cover each other's stalls. One-time exact merge of
// the two (m,l,acc) partials through the V LDS reused as f32 scratch.
// grid 256 (8b x 32 q-blocks of 128), 512 thr, 1 block/CU.
// ---------------------------------------------------------------------------
__global__ __launch_bounds__(512, 2) void attn_kernel(
    const unsigned short* __restrict__ Qm, const unsigned short* __restrict__ Km,
    const unsigned short* __restrict__ Vm, const float* __restrict__ gamma,
    float* __restrict__ out)
{
    __shared__ unsigned short Vs[2][2][CC * KVB];  // [half][buf] 4x32KB
    __shared__ float mArr[2][4][32];
    __shared__ float lArr[2][4][32];

    // XCD swizzle: each XCD gets one batch's 32 q-blocks (K+V fit its 4MB L2)
    const int bid = ((blockIdx.x & 7) << 5) + (blockIdx.x >> 3);
    const int b = bid >> 5;
    const int q0 = (bid & 31) * QB;

    const int t = threadIdx.x;
    const int wave = t >> 6;
    const int lane = t & 63;
    const int q_ = lane & 31;     // q / c row within 32
    const int hi = lane >> 5;
    const int s = wave & 3;       // q-slice
    const int h = wave >> 2;      // kv-half (== staging group t>>8)

    const int qrow = q0 + s * 32 + q_;

    // Q B-frags (persistent): B[k=d][col=q], qf[kh] elem e: Q[qrow][16kh+8hi+e]
    s16x8 qf[2];
#pragma unroll
    for (int kh = 0; kh < 2; ++kh)
        qf[kh] = *(const s16x8*)(Qm + ((size_t)b * NPIX + qrow) * 32 + kh * 16 + hi * 8);

    f32x16 acc[8];
#pragma unroll
    for (int ct = 0; ct < 8; ++ct) acc[ct] = (f32x16){};

    float mrun = -__builtin_inff();
    float lrun = 0.f;  // per-lane partial over this lane's m's; +shfl(32) at end

    const unsigned short* Kg = Km + (size_t)b * NPIX * 32;
    const unsigned short* Vg = Vm + (size_t)b * CC * NPIX;

    // V staging (global_load_lds): per half, 256 threads cover the 32KB tile.
    // Linear LDS dest (16B/thread); source column pre-swizzled (rule #21).
    const int tg = t & 255;
    const int vr0 = tg >> 3;                   // 0..31
    const int cg = (tg & 7) ^ (vr0 & 7);
    const unsigned short* vsrc = Vg + (size_t)vr0 * NPIX + cg * 8;

#define STAGE_V(tile, buf_)                                                    \
    {                                                                          \
        const int mm_ = h * 2048 + (tile) * KVB;                               \
        _Pragma("unroll")                                                      \
        for (int i_ = 0; i_ < 8; ++i_)                                         \
            __builtin_amdgcn_global_load_lds(                                  \
                (const __attribute__((address_space(1))) void*)(vsrc + (size_t)i_ * 32 * NPIX + mm_), \
                (__attribute__((address_space(3))) void*)(&Vs[h][buf_][i_ * 2048 + tg * 8]), \
                16, 0, 0);                                                     \
    }

    // K A-frags: A[row=m][k=d], kf[mt][kh] elem e: K[m0+32mt+q_][16kh+8hi+e]
    s16x8 kf[2][2];
#define LOAD_KF(mm_)                                                           \
    {                                                                          \
        _Pragma("unroll")                                                      \
        for (int mt_ = 0; mt_ < 2; ++mt_)                                      \
            _Pragma("unroll")                                                  \
            for (int kh_ = 0; kh_ < 2; ++kh_)                                  \
                kf[mt_][kh_] = *(const s16x8*)(Kg + (size_t)((mm_) + 32 * mt_ + q_) * 32 + kh_ * 16 + hi * 8); \
    }

    // prologue: stage tile 0 of this half into buf 0; K frags for tile 0
    STAGE_V(0, 0)
    LOAD_KF(h * 2048)

    int cur = 0;
    for (int it = 0; it < NT2; ++it) {
        __syncthreads();  // drains tile-it staging (vmcnt) + prev reads done

        // issue next tile's staging into the other buffer (flies across compute)
        if (it < NT2 - 1) STAGE_V(it + 1, cur ^ 1)

        // QK^T: S^T[m][q] via mfma32, m = (reg&3)+8*(reg>>2)+4hi (+32 for s1)
        f32x16 z = (f32x16){};
        f32x16 s0 = __builtin_amdgcn_mfma_f32_32x32x16_bf16(kf[0][0], qf[0], z, 0, 0, 0);
        s0 = __builtin_amdgcn_mfma_f32_32x32x16_bf16(kf[0][1], qf[1], s0, 0, 0, 0);
        f32x16 s1 = __builtin_amdgcn_mfma_f32_32x32x16_bf16(kf[1][0], qf[0], z, 0, 0, 0);
        s1 = __builtin_amdgcn_mfma_f32_32x32x16_bf16(kf[1][1], qf[1], s1, 0, 0, 0);

        // prefetch K frags for next tile (wrap within half; kf dead after QK)
        LOAD_KF(h * 2048 + (((it + 1) & (NT2 - 1))) * KVB)

        // online softmax (log2 domain; Q pre-scaled). Per-lane local max.
        float ml = -__builtin_inff();
#pragma unroll
        for (int r = 0; r < 16; ++r) ml = fmaxf(ml, s0[r]);
#pragma unroll
        for (int r = 0; r < 16; ++r) ml = fmaxf(ml, s1[r]);

        if (!__all(ml <= mrun + 8.f)) {  // defer-max violated (rare)
            ml = fmaxf(ml, __shfl_xor(ml, 32, 64));  // row max (pair lane)
            const float mnew = fmaxf(mrun, ml);
            const float alpha = __builtin_amdgcn_exp2f(mrun - mnew);
            mrun = mnew;
            lrun *= alpha;
#pragma unroll
            for (int ct = 0; ct < 8; ++ct) acc[ct] *= alpha;
        }

#pragma unroll
        for (int r = 0; r < 16; ++r) { s0[r] = __builtin_amdgcn_exp2f(s0[r] - mrun); lrun += s0[r]; }
#pragma unroll
        for (int r = 0; r < 16; ++r) { s1[r] = __builtin_amdgcn_exp2f(s1[r] - mrun); lrun += s1[r]; }

        // pack P words: w[mt][s][j]; w[.][s][0]=P[8s+4hi,+1], [1]=P[8s+4hi+2,+3]
        unsigned int w0[4][2], w1[4][2];
#pragma unroll
        for (int p = 0; p < 4; ++p) {
            w0[p][0] = cvt_pk_bf16(s0[4 * p + 0], s0[4 * p + 1]);
            w0[p][1] = cvt_pk_bf16(s0[4 * p + 2], s0[4 * p + 3]);
            w1[p][0] = cvt_pk_bf16(s1[4 * p + 0], s1[4 * p + 1]);
            w1[p][1] = cvt_pk_bf16(s1[4 * p + 2], s1[4 * p + 3]);
        }

        // PV per 16-m block t4: B-frag via 2 permlane32_swap; A from Vs[h][cur]
#pragma unroll
        for (int t4 = 0; t4 < 4; ++t4) {
            const int lt = t4 & 1;
            unsigned int a0 = (t4 < 2) ? w0[2 * lt][0] : w1[2 * lt][0];
            unsigned int b0 = (t4 < 2) ? w0[2 * lt + 1][0] : w1[2 * lt + 1][0];
            unsigned int a1 = (t4 < 2) ? w0[2 * lt][1] : w1[2 * lt][1];
            unsigned int b1 = (t4 < 2) ? w0[2 * lt + 1][1] : w1[2 * lt + 1][1];
            // D' = [D_lo|S_lo], S' = [D_hi|S_hi]
            asm("v_permlane32_swap_b32 %0, %1" : "+v"(a0), "+v"(b0));
            asm("v_permlane32_swap_b32 %0, %1" : "+v"(a1), "+v"(b1));
            u32x4 bw = {a0, a1, b0, b1};  // B words 0..3: P[16t4+8hi+2w..+1][q]
            const s16x8 pb = __builtin_bit_cast(s16x8, bw);

            __builtin_amdgcn_s_setprio(1);
#pragma unroll
            for (int ct = 0; ct < 8; ++ct) {
                const int c = 32 * ct + q_;
                const int slot = (2 * t4 + hi) ^ (c & 7);
                const s16x8 av = *(const s16x8*)(&Vs[h][cur][c * 64 + slot * 8]);
                acc[ct] = __builtin_amdgcn_mfma_f32_32x32x16_bf16(av, pb, acc[ct], 0, 0, 0);
            }
            __builtin_amdgcn_s_setprio(0);
        }

        cur ^= 1;
    }

    // ---- merge the two KV-half partials (exact) ----------------------------
    lrun += __shfl_xor(lrun, 32, 64);  // row total within half

    __syncthreads();  // all PV reads of Vs complete -> reusable as scratch

    if (lane < 32) { mArr[h][s][lane] = mrun; lArr[h][s][lane] = lrun; }
    __syncthreads();

    const float m_o = mArr[h ^ 1][s][q_];
    const float l_o = lArr[h ^ 1][s][q_];
    const float M = fmaxf(mrun, m_o);
    const float f = __builtin_amdgcn_exp2f(mrun - M);
    const float l_tot = lrun * f + l_o * __builtin_amdgcn_exp2f(m_o - M);

    float* S = (float*)&Vs[0][0][0];  // 32768 floats; [idx][s*64+lane]
    if (h == 1) {
#pragma unroll
        for (int ct = 0; ct < 8; ++ct)
#pragma unroll
            for (int r = 0; r < 16; ++r)
                S[(ct * 16 + r) * 256 + s * 64 + lane] = acc[ct][r] * f;
    }
    __syncthreads();

    if (h == 0) {
        const float inv = 1.f / l_tot;
        const float gm = gamma[0];
        float* out2 = out + (size_t)NB * CC * NPIX;
        const int n = qrow;
#pragma unroll
        for (int ct = 0; ct < 8; ++ct) {
#pragma unroll
            for (int r = 0; r < 16; ++r) {
                const int c = 32 * ct + (r & 3) + 8 * (r >> 2) + 4 * hi;
                const float val = (acc[ct][r] * f + S[(ct * 16 + r) * 256 + s * 64 + lane]) * inv;
                const size_t idx = ((size_t)b * CC + c) * NPIX + n;
                out[idx] = val;
                out2[idx] = gm * val;
            }
        }
    }
}

// ---------------------------------------------------------------------------
extern "C" void kernel_launch(void* const* d_in, const int* in_sizes, int n_in,
                              void* d_out, int out_size, void* d_ws, size_t ws_size,
                              hipStream_t stream) {
    (void)in_sizes; (void)n_in; (void)out_size; (void)ws_size;
    const float* x     = (const float*)d_in[0];
    const float* w1    = (const float*)d_in[1];
    const float* b1    = (const float*)d_in[2];
    const float* w2    = (const float*)d_in[3];
    const float* b2    = (const float*)d_in[4];
    const float* w3    = (const float*)d_in[5];
    const float* b3    = (const float*)d_in[6];
    const float* gamma = (const float*)d_in[7];
    float* out = (float*)d_out;

    unsigned short* Qm = (unsigned short*)d_ws;                       // 2 MB
    unsigned short* Km = Qm + (size_t)NB * NPIX * 32;                 // 2 MB
    unsigned short* Vm = Km + (size_t)NB * NPIX * 32;                 // 16 MB

    proj_gemm_kernel<<<NB * 64, 320, 0, stream>>>(x, w1, b1, w2, b2, w3, b3, Qm, Km, Vm);
    attn_kernel<<<NB * 32, 512, 0, stream>>>(Qm, Km, Vm, gamma, out);
}